// Round 1
// baseline (6855.405 us; speedup 1.0000x reference)
//
#include <hip/hip_runtime.h>
#include <math.h>

#define TT 64      // timesteps per x/out tile staged in LDS
#define XS 68      // padded LDS row stride (floats); 68*4=272B keeps 16B alignment, breaks bank conflicts

__device__ __forceinline__ float fast_sigmoid(float v) {
    return 1.0f / (1.0f + __expf(-v));
}

__device__ __forceinline__ float fast_tanh(float v) {
    float av = fabsf(v);
    float e = __expf(-2.0f * av);
    float r = (1.0f - e) / (1.0f + e);
    return copysignf(r, v);
}

__global__ __launch_bounds__(256, 1) void lstm2_fused(
    const float* __restrict__ x,      // [128][64][4096]
    const float* __restrict__ wih0,   // [256][64]
    const float* __restrict__ whh0,   // [256][64]
    const float* __restrict__ b0,     // [256]
    const float* __restrict__ wih1,   // [256][64]
    const float* __restrict__ whh1,   // [256][64]
    const float* __restrict__ b1,     // [256]
    float* __restrict__ out)          // [128][64][4096]
{
    const int b = blockIdx.x;   // batch element
    const int j = threadIdx.x;  // gate index 0..255 (i:0-63, f:64-127, g:128-191, o:192-255)

    __shared__ float xtile[TT * XS];   // xtile[tl][c], transposed x tile
    __shared__ float otile[64 * XS];   // otile[h][tl]
    __shared__ float h0vec[64];
    __shared__ float h1vec[64];
    __shared__ float g0[256];
    __shared__ float g1[256];

    // ---- weights resident in VGPRs: thread j holds row j of all 4 matrices ----
    float4 w0x[16], w0h[16], w1x[16], w1h[16];
    {
        const float4* p0 = (const float4*)(wih0 + j * 64);
        const float4* p1 = (const float4*)(whh0 + j * 64);
        const float4* p2 = (const float4*)(wih1 + j * 64);
        const float4* p3 = (const float4*)(whh1 + j * 64);
#pragma unroll
        for (int i = 0; i < 16; ++i) { w0x[i] = p0[i]; }
#pragma unroll
        for (int i = 0; i < 16; ++i) { w0h[i] = p1[i]; }
#pragma unroll
        for (int i = 0; i < 16; ++i) { w1x[i] = p2[i]; }
#pragma unroll
        for (int i = 0; i < 16; ++i) { w1h[i] = p3[i]; }
    }
    const float bias0 = b0[j];
    const float bias1 = b1[j];
    const bool is_tanh_gate = (j >= 128) && (j < 192);

    float c0 = 0.0f, c1 = 0.0f;   // cell states live in threads j<64

    if (j < 64) { h0vec[j] = 0.0f; h1vec[j] = 0.0f; }

    const float* xb = x + (size_t)b * 64 * 4096;
    float*       ob = out + (size_t)b * 64 * 4096;

    for (int t0 = 0; t0 < 4096; t0 += TT) {
        // ---- stage x tile, transposed to xtile[tl][c] (coalesced float4 global reads) ----
        for (int idx = j; idx < 64 * (TT / 4); idx += 256) {
            int c = idx >> 4;        // channel
            int q = idx & 15;        // float4 index along t
            float4 v = *(const float4*)(xb + (size_t)c * 4096 + t0 + 4 * q);
            xtile[(4 * q + 0) * XS + c] = v.x;
            xtile[(4 * q + 1) * XS + c] = v.y;
            xtile[(4 * q + 2) * XS + c] = v.z;
            xtile[(4 * q + 3) * XS + c] = v.w;
        }
        __syncthreads();

        for (int tl = 0; tl < TT; ++tl) {
            // ---- phase 1: layer0 gates (all 256 threads) ----
            {
                const float4* xv4 = (const float4*)(xtile + tl * XS);
                const float4* h04 = (const float4*)h0vec;
                float ax = 0.f, ay = 0.f, az = 0.f, aw = 0.f;
#pragma unroll
                for (int i = 0; i < 16; ++i) {
                    float4 v = xv4[i];
                    ax += w0x[i].x * v.x; ay += w0x[i].y * v.y;
                    az += w0x[i].z * v.z; aw += w0x[i].w * v.w;
                }
#pragma unroll
                for (int i = 0; i < 16; ++i) {
                    float4 v = h04[i];
                    ax += w0h[i].x * v.x; ay += w0h[i].y * v.y;
                    az += w0h[i].z * v.z; aw += w0h[i].w * v.w;
                }
                float acc = ((ax + ay) + (az + aw)) + bias0;
                g0[j] = is_tanh_gate ? fast_tanh(acc) : fast_sigmoid(acc);
            }
            __syncthreads();

            // ---- phase 2: layer0 cell/hidden update (wave 0) ----
            if (j < 64) {
                float i_ = g0[j];
                float f_ = g0[j + 64];
                float gg = g0[j + 128];
                float o_ = g0[j + 192];
                c0 = f_ * c0 + i_ * gg;
                float h0o = o_ * fast_tanh(c0);
                h0vec[j] = h0o;
            }
            __syncthreads();

            // ---- phase 3: layer1 gates (all 256 threads) ----
            {
                const float4* h04 = (const float4*)h0vec;
                const float4* h14 = (const float4*)h1vec;
                float ax = 0.f, ay = 0.f, az = 0.f, aw = 0.f;
#pragma unroll
                for (int i = 0; i < 16; ++i) {
                    float4 v = h04[i];
                    ax += w1x[i].x * v.x; ay += w1x[i].y * v.y;
                    az += w1x[i].z * v.z; aw += w1x[i].w * v.w;
                }
#pragma unroll
                for (int i = 0; i < 16; ++i) {
                    float4 v = h14[i];
                    ax += w1h[i].x * v.x; ay += w1h[i].y * v.y;
                    az += w1h[i].z * v.z; aw += w1h[i].w * v.w;
                }
                float acc = ((ax + ay) + (az + aw)) + bias1;
                g1[j] = is_tanh_gate ? fast_tanh(acc) : fast_sigmoid(acc);
            }
            __syncthreads();

            // ---- phase 4: layer1 update + output staging (wave 0) ----
            if (j < 64) {
                float i_ = g1[j];
                float f_ = g1[j + 64];
                float gg = g1[j + 128];
                float o_ = g1[j + 192];
                c1 = f_ * c1 + i_ * gg;
                float h1o = o_ * fast_tanh(c1);
                h1vec[j] = h1o;
                otile[j * XS + tl] = h1o;
            }
            __syncthreads();
        }

        // ---- flush output tile (coalesced float4 writes along t) ----
        for (int idx = j; idx < 64 * (TT / 4); idx += 256) {
            int r = idx >> 4;
            int q = idx & 15;
            float4 v = *(const float4*)(otile + r * XS + 4 * q);
            *(float4*)(ob + (size_t)r * 4096 + t0 + 4 * q) = v;
        }
        __syncthreads();
    }
}

extern "C" void kernel_launch(void* const* d_in, const int* in_sizes, int n_in,
                              void* d_out, int out_size, void* d_ws, size_t ws_size,
                              hipStream_t stream) {
    const float* x    = (const float*)d_in[0];
    const float* wih0 = (const float*)d_in[1];
    const float* whh0 = (const float*)d_in[2];
    const float* b0   = (const float*)d_in[3];
    const float* wih1 = (const float*)d_in[4];
    const float* whh1 = (const float*)d_in[5];
    const float* b1   = (const float*)d_in[6];
    float* out = (float*)d_out;

    lstm2_fused<<<128, 256, 0, stream>>>(x, wih0, whh0, b0, wih1, whh1, b1, out);
}

// Round 2
// 3916.327 us; speedup vs baseline: 1.7505x; 1.7505x over previous
//
#include <hip/hip_runtime.h>
#include <math.h>

#define TT 64      // timesteps per x/out tile staged in LDS
#define XS 68      // padded LDS row stride (floats)

__device__ __forceinline__ float fast_sigmoid(float v) {
    return 1.0f / (1.0f + __expf(-v));
}

__device__ __forceinline__ float fast_tanh(float v) {
    float av = fabsf(v);
    float e = __expf(-2.0f * av);
    float r = (1.0f - e) / (1.0f + e);
    return copysignf(r, v);
}

// One block per batch element. 512 threads:
//   tid 0..255   = layer 0, gate j = tid
//   tid 256..511 = layer 1, gate j = tid-256
// Layers are SKEWED: at iteration n, layer0 processes timestep n, layer1
// processes timestep n-1 (its input h0[n-1] was produced last iteration).
// 2 barriers per iteration. h vectors double-buffered in LDS.
__global__ __launch_bounds__(512) void lstm2_skew(
    const float* __restrict__ x,      // [128][64][4096]
    const float* __restrict__ wih0,   // [256][64]
    const float* __restrict__ whh0,   // [256][64]
    const float* __restrict__ b0,     // [256]
    const float* __restrict__ wih1,   // [256][64]
    const float* __restrict__ whh1,   // [256][64]
    const float* __restrict__ b1,     // [256]
    float* __restrict__ out)          // [128][64][4096]
{
    const int b   = blockIdx.x;
    const int tid = threadIdx.x;
    const int layer = tid >> 8;       // wave-uniform (waves 0-3 = L0, 4-7 = L1)
    const int j   = tid & 255;

    __shared__ float xt[TT * XS];     // xt[tl][c] transposed x tile
    __shared__ float ot[64 * XS];     // ot[h][tl] output staging
    __shared__ float h0buf[2][64];    // double-buffered hidden, layer0
    __shared__ float h1buf[2][64];    // double-buffered hidden, layer1
    __shared__ float g0[256];
    __shared__ float g1[256];

    // Per-thread weights: one gate row of one layer (128 floats = 32 float4).
    float4 wx[16], wh[16];
    {
        const float* wxp = (layer == 0 ? wih0 : wih1) + j * 64;
        const float* whp = (layer == 0 ? whh0 : whh1) + j * 64;
#pragma unroll
        for (int i = 0; i < 16; ++i) wx[i] = ((const float4*)wxp)[i];
#pragma unroll
        for (int i = 0; i < 16; ++i) wh[i] = ((const float4*)whp)[i];
    }
    const float bias = (layer == 0 ? b0 : b1)[j];
    const bool tanh_gate = (j >= 128) && (j < 192);  // wave-uniform (wave 2/6)

    float cst = 0.0f;   // cell state: live in tid<64 (c0) and tid 256..319 (c1)

    if (tid < 64) {
        h0buf[0][tid] = 0.f; h0buf[1][tid] = 0.f;
        h1buf[0][tid] = 0.f; h1buf[1][tid] = 0.f;
    }

    const float* xb = x   + (size_t)b * 64 * 4096;
    float*       ob = out + (size_t)b * 64 * 4096;

    for (int n = 0; n <= 4096; ++n) {
        // ---- stage next x tile (every 64 iters); barrier covers h-init at n=0 ----
        if ((n & 63) == 0 && n < 4096) {
            for (int idx = tid; idx < 64 * 16; idx += 512) {
                int c = idx >> 4;      // channel
                int q = idx & 15;      // float4 index along t
                float4 v = *(const float4*)(xb + (size_t)c * 4096 + n + 4 * q);
                xt[(4 * q + 0) * XS + c] = v.x;
                xt[(4 * q + 1) * XS + c] = v.y;
                xt[(4 * q + 2) * XS + c] = v.z;
                xt[(4 * q + 3) * XS + c] = v.w;
            }
            __syncthreads();
        }

        // ---- phase A: both layers' gate GEMVs concurrently ----
        if (layer == 0) {
            if (n < 4096) {
                const float4* av = (const float4*)(xt + (n & 63) * XS);
                const float4* hv = (const float4*)(h0buf[n & 1]);
                float a0=0,a1=0,a2=0,a3=0,b0_=0,b1_=0,b2_=0,b3_=0;
#pragma unroll
                for (int i = 0; i < 16; ++i) {
                    float4 v = av[i];
                    a0 += wx[i].x * v.x; a1 += wx[i].y * v.y;
                    a2 += wx[i].z * v.z; a3 += wx[i].w * v.w;
                }
#pragma unroll
                for (int i = 0; i < 16; ++i) {
                    float4 v = hv[i];
                    b0_ += wh[i].x * v.x; b1_ += wh[i].y * v.y;
                    b2_ += wh[i].z * v.z; b3_ += wh[i].w * v.w;
                }
                float acc = ((a0 + a1) + (a2 + a3)) + ((b0_ + b1_) + (b2_ + b3_)) + bias;
                g0[j] = tanh_gate ? fast_tanh(acc) : fast_sigmoid(acc);
            }
        } else {
            if (n >= 1) {
                const float4* av = (const float4*)(h0buf[n & 1]);   // input = h0[n-1]
                const float4* hv = (const float4*)(h1buf[n & 1]);   // recurrent h1[n-2]
                float a0=0,a1=0,a2=0,a3=0,b0_=0,b1_=0,b2_=0,b3_=0;
#pragma unroll
                for (int i = 0; i < 16; ++i) {
                    float4 v = av[i];
                    a0 += wx[i].x * v.x; a1 += wx[i].y * v.y;
                    a2 += wx[i].z * v.z; a3 += wx[i].w * v.w;
                }
#pragma unroll
                for (int i = 0; i < 16; ++i) {
                    float4 v = hv[i];
                    b0_ += wh[i].x * v.x; b1_ += wh[i].y * v.y;
                    b2_ += wh[i].z * v.z; b3_ += wh[i].w * v.w;
                }
                float acc = ((a0 + a1) + (a2 + a3)) + ((b0_ + b1_) + (b2_ + b3_)) + bias;
                g1[j] = tanh_gate ? fast_tanh(acc) : fast_sigmoid(acc);
            }
        }
        __syncthreads();

        // ---- phase B: cell/hidden updates, both layers in parallel waves ----
        if (tid < 64) {                       // layer 0 update (wave 0)
            if (n < 4096) {
                float i_ = g0[tid];
                float f_ = g0[tid + 64];
                float gg = g0[tid + 128];
                float o_ = g0[tid + 192];
                cst = f_ * cst + i_ * gg;
                h0buf[(n + 1) & 1][tid] = o_ * fast_tanh(cst);
            }
        } else if (tid >= 256 && tid < 320) { // layer 1 update (wave 4)
            if (n >= 1) {
                int k = tid - 256;
                float i_ = g1[k];
                float f_ = g1[k + 64];
                float gg = g1[k + 128];
                float o_ = g1[k + 192];
                cst = f_ * cst + i_ * gg;
                float h = o_ * fast_tanh(cst);
                h1buf[(n + 1) & 1][k] = h;
                ot[k * XS + ((n - 1) & 63)] = h;
            }
        }
        __syncthreads();

        // ---- flush output tile every 64 iters (t1 range [n-64, n-1]) ----
        if (n > 0 && (n & 63) == 0) {
            int t0f = n - 64;
            for (int idx = tid; idx < 64 * 16; idx += 512) {
                int r = idx >> 4;
                int q = idx & 15;
                float4 v = *(const float4*)(ot + r * XS + 4 * q);
                *(float4*)(ob + (size_t)r * 4096 + t0f + 4 * q) = v;
            }
            // no barrier needed: next write to ot happens after next iter's bar1
        }
    }
}

extern "C" void kernel_launch(void* const* d_in, const int* in_sizes, int n_in,
                              void* d_out, int out_size, void* d_ws, size_t ws_size,
                              hipStream_t stream) {
    const float* x    = (const float*)d_in[0];
    const float* wih0 = (const float*)d_in[1];
    const float* whh0 = (const float*)d_in[2];
    const float* b0   = (const float*)d_in[3];
    const float* wih1 = (const float*)d_in[4];
    const float* whh1 = (const float*)d_in[5];
    const float* b1   = (const float*)d_in[6];
    float* out = (float*)d_out;

    lstm2_skew<<<128, 512, 0, stream>>>(x, wih0, whh0, b0, wih1, whh1, b1, out);
}